// Round 1
// 585.366 us; speedup vs baseline: 1.1987x; 1.1987x over previous
//
#include <hip/hip_runtime.h>

// 3-layer LSTM (T=1024,B=512,F=32,H1=32,H2=8,H3=8) + locked dropout.
//
// R11: barrier-free wave-specialized producer/consumer, ONE kernel.
//  - wave0: L1 recurrence self-contained (2 gate rows/lane; i/f/g/o gathered
//    with two __shfl_xor(.,32) instead of LDS+barrier). h1 -> 128-step LDS
//    ring. Critical path/step: 8 broadcast ds_read_b128 + 64 FMA + act +
//    2 shfl + tanh + 1 ds_write. No s_barrier anywhere in the loop.
//  - wave1: fused skewed L2(i-1)/L3(i-2) consumer (R10 dot structure),
//    reads h1 ring, polls wave0 progress once per 8 steps (acquire).
//    Direct out stores (no barrier path exists to protect).
//  - wave2: xg producer (Wih1 @ x + bias) into a 64-step LDS ring; x staged
//    global->reg->LDS in 16-step tiles (double-buffered regs). Eliminates
//    the separate xg kernel and its 512MB HBM round-trip.
//  - Sync: 3 LDS progress flags, amortized release/acquire polling.
//    prog0(w0,/8) prog1(w1,/16) prog2(w2,/16). Bounded spins (no hang).
//    Deadlock-free: w2 throttles at prog0+40..55 ahead, w0 needs +34;
//    w0 throttles at prog1+48..128 behind, w1 lags only ~10.

constexpr int T = 1024, B = 512, F = 32;
constexpr int H1 = 32, H2 = 8, H3 = 8;
constexpr int G1 = 4 * H1;          // 128 gate rows, layer 1
constexpr int HR = 128;             // h1 ring length (steps), 16KB
constexpr int XR = 64;              // xg ring length (steps), 32KB
constexpr int OUT_STRIDE = B * H3;  // 4096

#define PIN(v) asm volatile("" : "+v"(v))

#if __has_builtin(__builtin_amdgcn_rcpf)
#define RCPF(x) __builtin_amdgcn_rcpf(x)
#else
#define RCPF(x) (1.0f / (x))
#endif
#if __has_builtin(__builtin_amdgcn_exp2f)
#define EXP2F(x) __builtin_amdgcn_exp2f(x)
#else
#define EXP2F(x) exp2f(x)
#endif

#define SIG_CM (-1.4426950408889634f)

__device__ __forceinline__ float act_f(float v, float cm, float ka, float kb) {
    return fmaf(ka, RCPF(1.0f + EXP2F(v * cm)), kb);
}
__device__ __forceinline__ float tanh_fast(float v) {
    return fmaf(2.0f, RCPF(1.0f + EXP2F(v * (2.0f * SIG_CM))), -1.0f);
}

// macro params avoid float4 member names x/y/z/w (R1 lesson)
#define FMA4(ACC, WARR, VEC, BASE)                                             \
    ACC = fmaf(WARR[(BASE) + 0], VEC.x, ACC);                                  \
    ACC = fmaf(WARR[(BASE) + 1], VEC.y, ACC);                                  \
    ACC = fmaf(WARR[(BASE) + 2], VEC.z, ACC);                                  \
    ACC = fmaf(WARR[(BASE) + 3], VEC.w, ACC);

#define LDS_ACQ(p)    __hip_atomic_load((p), __ATOMIC_ACQUIRE, __HIP_MEMORY_SCOPE_WORKGROUP)
#define LDS_REL(p, v) __hip_atomic_store((p), (v), __ATOMIC_RELEASE, __HIP_MEMORY_SCOPE_WORKGROUP)
// bounded spin: correctness valve against a compiler/sync surprise turning
// into a GPU hang; cap ~0.5s, never reached when logic is right.
#define SPIN_UNTIL(EXPR)                                                       \
    do {                                                                       \
        int _g = 0;                                                            \
        while (!(EXPR)) {                                                      \
            __builtin_amdgcn_s_sleep(2);                                       \
            if (++_g > (1 << 22)) break;                                       \
        }                                                                      \
    } while (0)

__global__ __launch_bounds__(192, 1) void lstm3_fused_kernel(
    const float* __restrict__ x,
    const float* __restrict__ Wih1, const float* __restrict__ Whh1,
    const float* __restrict__ bih1, const float* __restrict__ bhh1,
    const float* __restrict__ Wih2, const float* __restrict__ Whh2,
    const float* __restrict__ bih2, const float* __restrict__ bhh2,
    const float* __restrict__ Wih3, const float* __restrict__ Whh3,
    const float* __restrict__ bih3, const float* __restrict__ bhh3,
    const float* __restrict__ mask1, const float* __restrict__ mask2,
    const float* __restrict__ mask3,
    float* __restrict__ out)
{
    const int tid = threadIdx.x;
    const int lane = tid & 63;
    const int wid = tid >> 6;
    const int b = blockIdx.x;

    __shared__ __align__(16) float h1ring[HR][H1];   // 16 KB
    __shared__ __align__(16) float xgring[XR][G1];   // 32 KB
    __shared__ __align__(16) float xstage[32][F];    //  4 KB (2 x 16-step tiles)
    __shared__ __align__(16) float sh23[2][16];      // wave1-private h2|h3
    __shared__ int prog0, prog1, prog2;

    if (tid == 0) { prog0 = 0; prog1 = 0; prog2 = 0; }
    if (wid == 0 && lane < H1) h1ring[HR - 1][lane] = 0.f;  // step -1 slot
    if (wid == 1 && lane < 16) { sh23[0][lane] = 0.f; sh23[1][lane] = 0.f; }
    __syncthreads();  // the ONLY barrier in the kernel

    if (wid == 2) {
        // ================= wave 2: xg producer =================
        // rows lane and lane+64; xg[t][r] = dot(Wih1[r], x[t][b]) + bias[r]
        float wi0[F], wi1[F];
#pragma unroll
        for (int k = 0; k < F; ++k) wi0[k] = Wih1[lane * F + k];
#pragma unroll
        for (int k = 0; k < F; ++k) wi1[k] = Wih1[(lane + 64) * F + k];
        const float bias0 = bih1[lane] + bhh1[lane];
        const float bias1 = bih1[lane + 64] + bhh1[lane + 64];
#pragma unroll
        for (int k = 0; k < F; ++k) { PIN(wi0[k]); PIN(wi1[k]); }

        const float4* x4 = (const float4*)x;  // x[t][b][f]: t-stride 4096 f4
        float4* xr4 = (float4*)xstage;
        const int ttq = lane >> 3, ffq = lane & 7;  // lane -> (step-in-tile, f4)

        // prologue: tile0 -> LDS (one exposed vmem latency), tile1 -> regs
        float4 sA = x4[(size_t)(0 + ttq) * 4096 + b * 8 + ffq];
        float4 sB = x4[(size_t)(8 + ttq) * 4096 + b * 8 + ffq];
        xr4[(ttq & 31) * 8 + ffq] = sA;
        xr4[((8 + ttq) & 31) * 8 + ffq] = sB;
        sA = x4[(size_t)(16 + ttq) * 4096 + b * 8 + ffq];
        sB = x4[(size_t)(24 + ttq) * 4096 + b * 8 + ffq];

        for (int t = 0; t < T; ++t) {
            if ((t & 15) == 0) {
                const int need = t - 40;  // xg ring backpressure vs wave0
                if (need > 0) SPIN_UNTIL(LDS_ACQ(&prog0) >= need);
                const int wt = t + 16;
                if (wt < T) {
                    xr4[((wt + ttq) & 31) * 8 + ffq] = sA;       // staged 16
                    xr4[((wt + 8 + ttq) & 31) * 8 + ffq] = sB;   // steps ago
                    const int lt = t + 32;
                    if (lt < T) {
                        sA = x4[(size_t)(lt + ttq) * 4096 + b * 8 + ffq];
                        sB = x4[(size_t)(lt + 8 + ttq) * 4096 + b * 8 + ffq];
                    }
                }
            }
            const float4* xp = (const float4*)xstage[t & 31];  // broadcast
            float aA = bias0, aB = 0.f, cA = bias1, cB = 0.f;
#pragma unroll
            for (int q = 0; q < 8; q += 2) {
                const float4 v0 = xp[q], v1 = xp[q + 1];
                FMA4(aA, wi0, v0, q * 4); FMA4(aB, wi0, v1, q * 4 + 4);
                FMA4(cA, wi1, v0, q * 4); FMA4(cB, wi1, v1, q * 4 + 4);
            }
            xgring[t & (XR - 1)][lane] = aA + aB;        // 2-way bank, free
            xgring[t & (XR - 1)][lane + 64] = cA + cB;
            if ((t & 15) == 15) LDS_REL(&prog2, t + 1);
        }
    } else if (wid == 0) {
        // ================= wave 0: L1 recurrence =================
        // rows: r0=lane (0..63 = i|f over halves), r1=lane+64 (64..127 = g|o)
        float w0[H1], w1[H1];
#pragma unroll
        for (int k = 0; k < H1; ++k) w0[k] = Whh1[lane * H1 + k];
#pragma unroll
        for (int k = 0; k < H1; ++k) w1[k] = Whh1[(lane + 64) * H1 + k];
#pragma unroll
        for (int k = 0; k < H1; ++k) { PIN(w0[k]); PIN(w1[k]); }
        // g0 rows are all sigmoid; g1: lanes<32 -> g-gate (tanh), else o (sig)
        const float cm1 = (lane < 32) ? 2.0f * SIG_CM : SIG_CM;
        const float ka1 = (lane < 32) ? 2.0f : 1.0f;
        const float kb1 = (lane < 32) ? -1.0f : 0.0f;
        float c1 = 0.f;

        SPIN_UNTIL(LDS_ACQ(&prog2) >= ((34 < T) ? 34 : T));
        float pa = xgring[0][lane], pb = xgring[0][lane + 64];
        float na = xgring[1][lane], nb = xgring[1][lane + 64];

        for (int i = 0; i < T; ++i) {
            if ((i & 31) == 0 && i) {  // xg availability, amortized /32
                int tgt = i + 34; if (tgt > T) tgt = T;
                SPIN_UNTIL(LDS_ACQ(&prog2) >= tgt);
            }
            if ((i & 63) == 0 && i >= 64)  // h1 ring backpressure vs wave1
                SPIN_UNTIL(LDS_ACQ(&prog1) >= i - 48);

            const float4* h1p = (const float4*)h1ring[(i - 1) & (HR - 1)];
            float aA = 0.f, aB = 0.f, aC = 0.f, aD = 0.f;
            float bA = 0.f, bB = 0.f, bC = 0.f, bD = 0.f;
            {
                const float4 v0 = h1p[0], v1 = h1p[1], v2 = h1p[2], v3 = h1p[3];
                FMA4(aA, w0, v0, 0);  FMA4(aB, w0, v1, 4);
                FMA4(aC, w0, v2, 8);  FMA4(aD, w0, v3, 12);
                FMA4(bA, w1, v0, 0);  FMA4(bB, w1, v1, 4);
                FMA4(bC, w1, v2, 8);  FMA4(bD, w1, v3, 12);
            }
            {
                const float4 v4 = h1p[4], v5 = h1p[5], v6 = h1p[6], v7 = h1p[7];
                FMA4(aA, w0, v4, 16); FMA4(aB, w0, v5, 20);
                FMA4(aC, w0, v6, 24); FMA4(aD, w0, v7, 28);
                FMA4(bA, w1, v4, 16); FMA4(bB, w1, v5, 20);
                FMA4(bC, w1, v6, 24); FMA4(bD, w1, v7, 28);
            }
            const float a0 = pa + ((aA + aB) + (aC + aD));
            const float a1 = pb + ((bA + bB) + (bC + bD));
            const float g0 = act_f(a0, SIG_CM, 1.0f, 0.0f);  // i|f
            const float g1 = act_f(a1, cm1, ka1, kb1);       // g|o
            pa = na; pb = nb;
            {   // prefetch xg(i+2), clamped (slot guaranteed by poll window)
                int tn = i + 2; if (tn > T - 1) tn = T - 1;
                na = xgring[tn & (XR - 1)][lane];
                nb = xgring[tn & (XR - 1)][lane + 64];
            }
            // gate exchange: lanes j<32 get f=g0[j+32], o=g1[j+32].
            // (high lanes produce junk c1/h1 -- never written/read)
            const float f_ = __shfl_xor(g0, 32);
            const float o_ = __shfl_xor(g1, 32);
            c1 = fmaf(f_, c1, g0 * g1);                  // f*c1 + i*g
            const float h1v = o_ * tanh_fast(c1);
            if (lane < H1) h1ring[i & (HR - 1)][lane] = h1v;
            if ((i & 7) == 7) LDS_REL(&prog0, i + 1);
        }
    } else {
        // ========== wave 1: fused skewed L2(i-1)/L3(i-2) consumer ==========
        float wreg[48];
        float biasX, m3;
        const int r = lane & 31;
        const bool lower = (lane < 32);
        if (lower) {  // L2 gate row r (mask1 folded into Wih2)
#pragma unroll
            for (int k = 0; k < H1; ++k) wreg[k] = Wih2[r * H1 + k] * mask1[b * H1 + k];
#pragma unroll
            for (int k = 0; k < H2; ++k) wreg[32 + k] = Whh2[r * H2 + k];
#pragma unroll
            for (int k = 0; k < H3; ++k) wreg[40 + k] = 0.0f;
            biasX = bih2[r] + bhh2[r];
        } else {      // L3 gate row r (mask2 folded into Wih3)
#pragma unroll
            for (int k = 0; k < H1; ++k) wreg[k] = 0.0f;
#pragma unroll
            for (int k = 0; k < H2; ++k) wreg[32 + k] = Wih3[r * H2 + k] * mask2[b * H2 + k];
#pragma unroll
            for (int k = 0; k < H3; ++k) wreg[40 + k] = Whh3[r * H3 + k];
            biasX = bih3[r] + bhh3[r];
        }
        const int sec = r >> 3;
        const float cmX = (sec == 2) ? 2.0f * SIG_CM : SIG_CM;
        const float kaX = (sec == 2) ? 2.0f : 1.0f;
        const float kbX = (sec == 2) ? -1.0f : 0.0f;
        m3 = mask3[b * H3 + (lane & 7)];
        const int thresh = lower ? 1 : 2;
        const int gbase = (lane & 32) + (lane & 7);
#pragma unroll
        for (int k = 0; k < 48; ++k) PIN(wreg[k]);

        float c23 = 0.f;
        for (int i = 0; i <= T + 1; ++i) {
            if ((i & 7) == 0) {  // h1 availability, amortized /8
                int tgt = i + 7; if (tgt > T) tgt = T;
                SPIN_UNTIL(LDS_ACQ(&prog0) >= tgt);
            }
            const int par = i & 1;
            const float4* h1p = (const float4*)h1ring[(i - 1) & (HR - 1)];
            const float4* up = (const float4*)sh23[par ^ 1];
            float s0 = 0.f, s1 = 0.f, s2 = 0.f, s3 = 0.f;
            {
                const float4 v0 = h1p[0], v1 = h1p[1], v2 = h1p[2];
                FMA4(s0, wreg, v0, 0);  FMA4(s0, wreg, v1, 4);  FMA4(s0, wreg, v2, 8);
            }
            {
                const float4 v3 = h1p[3], v4 = h1p[4], v5 = h1p[5];
                FMA4(s1, wreg, v3, 12); FMA4(s1, wreg, v4, 16); FMA4(s1, wreg, v5, 20);
            }
            {
                const float4 v6 = h1p[6], v7 = h1p[7], u0 = up[0];
                FMA4(s2, wreg, v6, 24); FMA4(s2, wreg, v7, 28); FMA4(s2, wreg, u0, 32);
            }
            {
                const float4 u1 = up[1], u2 = up[2], u3 = up[3];
                FMA4(s3, wreg, u1, 36); FMA4(s3, wreg, u2, 40); FMA4(s3, wreg, u3, 44);
            }
            const float a23 = biasX + (s0 + s1) + (s2 + s3);
            const float rv = act_f(a23, cmX, kaX, kbX);
            const float gi = __shfl(rv, gbase);
            const float gf = __shfl(rv, gbase + 8);
            const float gg = __shfl(rv, gbase + 16);
            const float go = __shfl(rv, gbase + 24);
            c23 = (i >= thresh) ? fmaf(gf, c23, gi * gg) : 0.0f;
            const float hnew = go * tanh_fast(c23);  // h2(i-1) / h3(i-2)
            if (i >= 2 && (lane & 56) == 32)         // lanes 32-39: out(i-2)
                out[(size_t)(i - 2) * OUT_STRIDE + b * H3 + (lane & 7)] = hnew * m3;
            if ((lane & 24) == 0)                    // lanes 0-7 h2, 32-39 h3
                sh23[par][(lane & 7) | ((lane & 32) >> 2)] = hnew;
            if ((i & 15) == 15) LDS_REL(&prog1, i + 1);
        }
    }
}

extern "C" void kernel_launch(void* const* d_in, const int* in_sizes, int n_in,
                              void* d_out, int out_size, void* d_ws, size_t ws_size,
                              hipStream_t stream) {
    (void)in_sizes; (void)n_in; (void)out_size; (void)d_ws; (void)ws_size;
    const float* x     = (const float*)d_in[0];
    const float* Wih1  = (const float*)d_in[1];
    const float* Whh1  = (const float*)d_in[2];
    const float* bih1  = (const float*)d_in[3];
    const float* bhh1  = (const float*)d_in[4];
    const float* Wih2  = (const float*)d_in[5];
    const float* Whh2  = (const float*)d_in[6];
    const float* bih2  = (const float*)d_in[7];
    const float* bhh2  = (const float*)d_in[8];
    const float* Wih3  = (const float*)d_in[9];
    const float* Whh3  = (const float*)d_in[10];
    const float* bih3  = (const float*)d_in[11];
    const float* bhh3  = (const float*)d_in[12];
    const float* mask1 = (const float*)d_in[13];
    const float* mask2 = (const float*)d_in[14];
    const float* mask3 = (const float*)d_in[15];
    float* out = (float*)d_out;

    lstm3_fused_kernel<<<dim3(B), dim3(192), 0, stream>>>(
        x, Wih1, Whh1, bih1, bhh1,
        Wih2, Whh2, bih2, bhh2,
        Wih3, Whh3, bih3, bhh3,
        mask1, mask2, mask3, out);
}

// Round 4
// 539.197 us; speedup vs baseline: 1.3014x; 1.0856x over previous
//
#include <hip/hip_runtime.h>

// 3-layer LSTM (T=1024,B=512,F=32,H1=32,H2=8,H3=8) + locked dropout.
//
// R14: de-risk R12/R13's two failures (both ~5e-2 absmax, differing only in
// permlane consumption => the asm itself was broken, most likely register
// TYING: `float f_=g0; asm("+v"(f_),"+v"(g0))` lets RA coalesce f_ and g0
// into one register -> `v_permlane32_swap_b32 v5, v5` (in-place half swap,
// garbage gates).
//  - wave0 gate exchange now uses __builtin_amdgcn_permlane32_swap (SSA
//    pair result, tying impossible; semantics compiler-managed). With both
//    args = g0=[i|f]: out.x=[i|i], out.y=[f|f]. Fallback: R11's proven
//    __shfl_xor path if the builtin is missing.
//  - packed dots now plain C vector math on f32x2 (acc += a*b); HIP's
//    -ffp-contract=fast emits v_pk_fma_f32 where profitable; worst case
//    2x v_fma_f32 = R11 baseline. No asm op_sel risk.
//  - wave1's batched gate gather kept: 4x ds_bpermute + ONE waitcnt
//    (exactly what __shfl lowers to; deps flow through asm outputs).
// Structure (R11, proven): barrier-free producer/consumer.
//  wave0 = L1 recurrence, wave1 = fused skewed L2(i-1)/L3(i-2) + out,
//  wave2 = xg producer (x staged 16-step tiles). LDS progress flags with
//  amortized acquire/release polling, bounded spins (no hang possible).

constexpr int T = 1024, B = 512, F = 32;
constexpr int H1 = 32, H2 = 8, H3 = 8;
constexpr int G1 = 4 * H1;          // 128 gate rows, layer 1
constexpr int HR = 128;             // h1 ring length (steps), 16KB
constexpr int XR = 64;              // xg ring length (steps), 32KB
constexpr int OUT_STRIDE = B * H3;  // 4096

typedef float f32x2 __attribute__((ext_vector_type(2)));
typedef unsigned int u32x2 __attribute__((ext_vector_type(2)));

#define PIN(v) asm volatile("" : "+v"(v))

#if __has_builtin(__builtin_amdgcn_rcpf)
#define RCPF(x) __builtin_amdgcn_rcpf(x)
#else
#define RCPF(x) (1.0f / (x))
#endif
#if __has_builtin(__builtin_amdgcn_exp2f)
#define EXP2F(x) __builtin_amdgcn_exp2f(x)
#else
#define EXP2F(x) exp2f(x)
#endif

#if __has_builtin(__builtin_amdgcn_permlane32_swap)
#define HAVE_PLSWAP 1
#else
#define HAVE_PLSWAP 0
#endif

#define SIG_CM (-1.4426950408889634f)

__device__ __forceinline__ float act_f(float v, float cm, float ka, float kb) {
    return fmaf(ka, RCPF(1.0f + EXP2F(v * cm)), kb);
}
__device__ __forceinline__ float tanh_fast(float v) {
    return fmaf(2.0f, RCPF(1.0f + EXP2F(v * (2.0f * SIG_CM))), -1.0f);
}

// packed MAC: plain C vector math; -ffp-contract=fast -> v_pk_fma_f32
__device__ __forceinline__ void pkfma(f32x2& acc, f32x2 a, f32x2 b) {
    acc += a * b;
}

#define LDS_ACQ(p)    __hip_atomic_load((p), __ATOMIC_ACQUIRE, __HIP_MEMORY_SCOPE_WORKGROUP)
#define LDS_REL(p, v) __hip_atomic_store((p), (v), __ATOMIC_RELEASE, __HIP_MEMORY_SCOPE_WORKGROUP)
// bounded spin: correctness valve (cap ~0.5s); never reached when logic ok.
#define SPIN_UNTIL(EXPR)                                                       \
    do {                                                                       \
        int _g = 0;                                                            \
        while (!(EXPR)) {                                                      \
            __builtin_amdgcn_s_sleep(2);                                       \
            if (++_g > (1 << 22)) break;                                       \
        }                                                                      \
    } while (0)

__global__ __launch_bounds__(192, 1) void lstm3_fused_kernel(
    const float* __restrict__ x,
    const float* __restrict__ Wih1, const float* __restrict__ Whh1,
    const float* __restrict__ bih1, const float* __restrict__ bhh1,
    const float* __restrict__ Wih2, const float* __restrict__ Whh2,
    const float* __restrict__ bih2, const float* __restrict__ bhh2,
    const float* __restrict__ Wih3, const float* __restrict__ Whh3,
    const float* __restrict__ bih3, const float* __restrict__ bhh3,
    const float* __restrict__ mask1, const float* __restrict__ mask2,
    const float* __restrict__ mask3,
    float* __restrict__ out)
{
    const int tid = threadIdx.x;
    const int lane = tid & 63;
    const int wid = tid >> 6;
    const int b = blockIdx.x;

    __shared__ __align__(16) float h1ring[HR][H1];   // 16 KB
    __shared__ __align__(16) float xgring[XR][G1];   // 32 KB
    __shared__ __align__(16) float xstage[32][F];    //  4 KB (2 x 16-step tiles)
    __shared__ __align__(16) float sh23[2][16];      // wave1-private h2|h3
    __shared__ int prog0, prog1, prog2;

    if (tid == 0) { prog0 = 0; prog1 = 0; prog2 = 0; }
    if (wid == 0 && lane < H1) h1ring[HR - 1][lane] = 0.f;  // step -1 slot
    if (wid == 1 && lane < 16) { sh23[0][lane] = 0.f; sh23[1][lane] = 0.f; }
    __syncthreads();  // the ONLY barrier in the kernel

    if (wid == 2) {
        // ================= wave 2: xg producer =================
        // rows lane and lane+64; xg[t][r] = dot(Wih1[r], x[t][b]) + bias[r]
        f32x2 wi0[16], wi1[16];
#pragma unroll
        for (int k = 0; k < 16; ++k) {
            wi0[k] = f32x2{Wih1[lane * F + 2 * k], Wih1[lane * F + 2 * k + 1]};
            wi1[k] = f32x2{Wih1[(lane + 64) * F + 2 * k], Wih1[(lane + 64) * F + 2 * k + 1]};
        }
        const float bias0 = bih1[lane] + bhh1[lane];
        const float bias1 = bih1[lane + 64] + bhh1[lane + 64];
#pragma unroll
        for (int k = 0; k < 16; ++k) { PIN(wi0[k]); PIN(wi1[k]); }

        const float4* x4 = (const float4*)x;  // x[t][b][f]: t-stride 4096 f4
        float4* xr4 = (float4*)xstage;
        const int ttq = lane >> 3, ffq = lane & 7;  // lane -> (step-in-tile, f4)

        // prologue: tile0 -> LDS (one exposed vmem latency), tile1 -> regs
        float4 sA = x4[(size_t)(0 + ttq) * 4096 + b * 8 + ffq];
        float4 sB = x4[(size_t)(8 + ttq) * 4096 + b * 8 + ffq];
        xr4[(ttq & 31) * 8 + ffq] = sA;
        xr4[((8 + ttq) & 31) * 8 + ffq] = sB;
        sA = x4[(size_t)(16 + ttq) * 4096 + b * 8 + ffq];
        sB = x4[(size_t)(24 + ttq) * 4096 + b * 8 + ffq];

        for (int t = 0; t < T; ++t) {
            if ((t & 15) == 0) {
                const int need = t - 40;  // xg ring backpressure vs wave0
                if (need > 0) SPIN_UNTIL(LDS_ACQ(&prog0) >= need);
                const int wt = t + 16;
                if (wt < T) {
                    xr4[((wt + ttq) & 31) * 8 + ffq] = sA;       // staged 16
                    xr4[((wt + 8 + ttq) & 31) * 8 + ffq] = sB;   // steps ago
                    const int lt = t + 32;
                    if (lt < T) {
                        sA = x4[(size_t)(lt + ttq) * 4096 + b * 8 + ffq];
                        sB = x4[(size_t)(lt + 8 + ttq) * 4096 + b * 8 + ffq];
                    }
                }
            }
            const float4* xp = (const float4*)xstage[t & 31];  // broadcast
            f32x2 aA = f32x2{bias0, 0.f}, aB = f32x2{0.f, 0.f};
            f32x2 cA = f32x2{bias1, 0.f}, cB = f32x2{0.f, 0.f};
#pragma unroll
            for (int q = 0; q < 8; ++q) {
                const float4 v = xp[q];
                const f32x2 lo = f32x2{v.x, v.y}, hi = f32x2{v.z, v.w};
                pkfma(aA, wi0[2 * q], lo); pkfma(aB, wi0[2 * q + 1], hi);
                pkfma(cA, wi1[2 * q], lo); pkfma(cB, wi1[2 * q + 1], hi);
            }
            const f32x2 sa = aA + aB, sc = cA + cB;
            xgring[t & (XR - 1)][lane] = sa.x + sa.y;    // 2-way bank, free
            xgring[t & (XR - 1)][lane + 64] = sc.x + sc.y;
            if ((t & 15) == 15) LDS_REL(&prog2, t + 1);
        }
    } else if (wid == 0) {
        // ================= wave 0: L1 recurrence =================
        // rows: r0=lane (0..63 = i|f over halves), r1=lane+64 (64..127 = g|o)
        f32x2 w0[16], w1[16];
#pragma unroll
        for (int k = 0; k < 16; ++k) {
            w0[k] = f32x2{Whh1[lane * H1 + 2 * k], Whh1[lane * H1 + 2 * k + 1]};
            w1[k] = f32x2{Whh1[(lane + 64) * H1 + 2 * k], Whh1[(lane + 64) * H1 + 2 * k + 1]};
        }
#pragma unroll
        for (int k = 0; k < 16; ++k) { PIN(w0[k]); PIN(w1[k]); }
        // g0 rows are all sigmoid; g1: lanes<32 -> g-gate (tanh), else o (sig)
        const float cm1 = (lane < 32) ? 2.0f * SIG_CM : SIG_CM;
        const float ka1 = (lane < 32) ? 2.0f : 1.0f;
        const float kb1 = (lane < 32) ? -1.0f : 0.0f;
        float c1 = 0.f;

        SPIN_UNTIL(LDS_ACQ(&prog2) >= ((34 < T) ? 34 : T));
        float pa = xgring[0][lane], pb = xgring[0][lane + 64];
        float na = xgring[1][lane], nb = xgring[1][lane + 64];

        for (int i = 0; i < T; ++i) {
            if ((i & 31) == 0 && i) {  // xg availability, amortized /32
                int tgt = i + 34; if (tgt > T) tgt = T;
                SPIN_UNTIL(LDS_ACQ(&prog2) >= tgt);
            }
            if ((i & 63) == 0 && i >= 64)  // h1 ring backpressure vs wave1
                SPIN_UNTIL(LDS_ACQ(&prog1) >= i - 48);

            const float4* h1p = (const float4*)h1ring[(i - 1) & (HR - 1)];
            f32x2 A0 = f32x2{0.f, 0.f}, A1 = f32x2{0.f, 0.f};
            f32x2 B0 = f32x2{0.f, 0.f}, B1 = f32x2{0.f, 0.f};
#pragma unroll
            for (int q = 0; q < 8; ++q) {
                const float4 v = h1p[q];
                const f32x2 lo = f32x2{v.x, v.y}, hi = f32x2{v.z, v.w};
                pkfma(A0, w0[2 * q], lo); pkfma(A1, w0[2 * q + 1], hi);
                pkfma(B0, w1[2 * q], lo); pkfma(B1, w1[2 * q + 1], hi);
            }
            const f32x2 SA = A0 + A1, SB = B0 + B1;
            const float a0 = pa + (SA.x + SA.y);
            const float a1 = pb + (SB.x + SB.y);
            const float g0 = act_f(a0, SIG_CM, 1.0f, 0.0f);  // [i|f]
            const float g1 = act_f(a1, cm1, ka1, kb1);       // [g|o]
            pa = na; pb = nb;
            {   // prefetch xg(i+2), clamped (slot guaranteed by poll window)
                int tn = i + 2; if (tn > T - 1) tn = T - 1;
                na = xgring[tn & (XR - 1)][lane];
                nb = xgring[tn & (XR - 1)][lane + 64];
            }
            float h1v;
#if HAVE_PLSWAP
            // builtin returns {vdst_new, vsrc_new}; with both args = g0:
            // .x = [g0.lo|g0.lo] = [i|i], .y = [g0.hi|g0.hi] = [f|f].
            // SSA pair result -> no register-tying hazard (R12/R13 bug).
            const u32x2 pif = __builtin_amdgcn_permlane32_swap(
                __float_as_uint(g0), __float_as_uint(g0), false, false);
            const u32x2 pgo = __builtin_amdgcn_permlane32_swap(
                __float_as_uint(g1), __float_as_uint(g1), false, false);
            const float iv = __uint_as_float(pif.x);   // [i|i]
            const float fv = __uint_as_float(pif.y);   // [f|f]
            const float gv = __uint_as_float(pgo.x);   // [g|g]
            const float ov = __uint_as_float(pgo.y);   // [o|o]
            c1 = fmaf(fv, c1, iv * gv);                // c1 = f*c1 + i*g
            h1v = ov * tanh_fast(c1);                  // h1 = o*tanh(c1)
#else
            // R11-proven fallback: lanes<32 get f=g0[j+32], o=g1[j+32];
            // high lanes compute junk (never written).
            const float fv = __shfl_xor(g0, 32);
            const float ov = __shfl_xor(g1, 32);
            c1 = fmaf(fv, c1, g0 * g1);                // f*c1 + i*g (lanes<32)
            h1v = ov * tanh_fast(c1);
#endif
            if (lane < H1) h1ring[i & (HR - 1)][lane] = h1v;
            if ((i & 7) == 7) LDS_REL(&prog0, i + 1);
        }
    } else {
        // ========== wave 1: fused skewed L2(i-1)/L3(i-2) consumer ==========
        // 48-term dot over [h1(32) | h2(8) | h3(8)] as 24 f32x2 pairs.
        f32x2 wp[24];
        float biasX, m3;
        const int r = lane & 31;
        const bool lower = (lane < 32);
        if (lower) {  // L2 gate row r (mask1 folded into Wih2)
#pragma unroll
            for (int k = 0; k < 16; ++k)
                wp[k] = f32x2{Wih2[r * H1 + 2 * k] * mask1[b * H1 + 2 * k],
                              Wih2[r * H1 + 2 * k + 1] * mask1[b * H1 + 2 * k + 1]};
#pragma unroll
            for (int k = 0; k < 4; ++k)
                wp[16 + k] = f32x2{Whh2[r * H2 + 2 * k], Whh2[r * H2 + 2 * k + 1]};
#pragma unroll
            for (int k = 0; k < 4; ++k) wp[20 + k] = f32x2{0.f, 0.f};
            biasX = bih2[r] + bhh2[r];
        } else {      // L3 gate row r (mask2 folded into Wih3)
#pragma unroll
            for (int k = 0; k < 16; ++k) wp[k] = f32x2{0.f, 0.f};
#pragma unroll
            for (int k = 0; k < 4; ++k)
                wp[16 + k] = f32x2{Wih3[r * H2 + 2 * k] * mask2[b * H2 + 2 * k],
                                   Wih3[r * H2 + 2 * k + 1] * mask2[b * H2 + 2 * k + 1]};
#pragma unroll
            for (int k = 0; k < 4; ++k)
                wp[20 + k] = f32x2{Whh3[r * H3 + 2 * k], Whh3[r * H3 + 2 * k + 1]};
            biasX = bih3[r] + bhh3[r];
        }
        const int sec = r >> 3;
        const float cmX = (sec == 2) ? 2.0f * SIG_CM : SIG_CM;
        const float kaX = (sec == 2) ? 2.0f : 1.0f;
        const float kbX = (sec == 2) ? -1.0f : 0.0f;
        m3 = mask3[b * H3 + (lane & 7)];
        const int thresh = lower ? 1 : 2;
        const int gbase = (lane & 32) + (lane & 7);
        // byte indices for the batched ds_bpermute gather (loop-invariant)
        const int bx0 = 4 * (gbase + 0),  bx1 = 4 * (gbase + 8);
        const int bx2 = 4 * (gbase + 16), bx3 = 4 * (gbase + 24);
#pragma unroll
        for (int k = 0; k < 24; ++k) PIN(wp[k]);

        float c23 = 0.f;
        for (int i = 0; i <= T + 1; ++i) {
            if ((i & 7) == 0) {  // h1 availability, amortized /8
                int tgt = i + 7; if (tgt > T) tgt = T;
                SPIN_UNTIL(LDS_ACQ(&prog0) >= tgt);
            }
            const int par = i & 1;
            const float4* h1p = (const float4*)h1ring[(i - 1) & (HR - 1)];
            const float4* up = (const float4*)sh23[par ^ 1];
            f32x2 s0 = f32x2{0.f, 0.f}, s1 = f32x2{0.f, 0.f};
            f32x2 s2 = f32x2{0.f, 0.f}, s3 = f32x2{0.f, 0.f};
#pragma unroll
            for (int q = 0; q < 4; ++q) {
                const float4 v = h1p[q], w = h1p[q + 4];
                pkfma(s0, wp[2 * q], f32x2{v.x, v.y});
                pkfma(s0, wp[2 * q + 1], f32x2{v.z, v.w});
                pkfma(s1, wp[8 + 2 * q], f32x2{w.x, w.y});
                pkfma(s1, wp[8 + 2 * q + 1], f32x2{w.z, w.w});
            }
            {   // u-part (sh23-dependent tail, short chains)
                const float4 u0 = up[0], u1 = up[1], u2 = up[2], u3 = up[3];
                pkfma(s2, wp[16], f32x2{u0.x, u0.y});
                pkfma(s2, wp[17], f32x2{u0.z, u0.w});
                pkfma(s2, wp[18], f32x2{u1.x, u1.y});
                pkfma(s2, wp[19], f32x2{u1.z, u1.w});
                pkfma(s3, wp[20], f32x2{u2.x, u2.y});
                pkfma(s3, wp[21], f32x2{u2.z, u2.w});
                pkfma(s3, wp[22], f32x2{u3.x, u3.y});
                pkfma(s3, wp[23], f32x2{u3.z, u3.w});
            }
            const f32x2 st = (s0 + s1) + (s2 + s3);
            const float a23 = biasX + st.x + st.y;
            const float rv = act_f(a23, cmX, kaX, kbX);
            // batched gate gather: 4x ds_bpermute in flight, ONE waitcnt
            float gi, gf, gg, go;
            asm volatile(
                "ds_bpermute_b32 %0, %4, %8\n\t"
                "ds_bpermute_b32 %1, %5, %8\n\t"
                "ds_bpermute_b32 %2, %6, %8\n\t"
                "ds_bpermute_b32 %3, %7, %8\n\t"
                "s_waitcnt lgkmcnt(0)"
                : "=&v"(gi), "=&v"(gf), "=&v"(gg), "=&v"(go)
                : "v"(bx0), "v"(bx1), "v"(bx2), "v"(bx3), "v"(rv));
            c23 = (i >= thresh) ? fmaf(gf, c23, gi * gg) : 0.0f;
            const float hnew = go * tanh_fast(c23);  // h2(i-1) / h3(i-2)
            if (i >= 2 && (lane & 56) == 32)         // lanes 32-39: out(i-2)
                out[(size_t)(i - 2) * OUT_STRIDE + b * H3 + (lane & 7)] = hnew * m3;
            if ((lane & 24) == 0)                    // lanes 0-7 h2, 32-39 h3
                sh23[par][(lane & 7) | ((lane & 32) >> 2)] = hnew;
            if ((i & 15) == 15) LDS_REL(&prog1, i + 1);
        }
    }
}

extern "C" void kernel_launch(void* const* d_in, const int* in_sizes, int n_in,
                              void* d_out, int out_size, void* d_ws, size_t ws_size,
                              hipStream_t stream) {
    (void)in_sizes; (void)n_in; (void)out_size; (void)d_ws; (void)ws_size;
    const float* x     = (const float*)d_in[0];
    const float* Wih1  = (const float*)d_in[1];
    const float* Whh1  = (const float*)d_in[2];
    const float* bih1  = (const float*)d_in[3];
    const float* bhh1  = (const float*)d_in[4];
    const float* Wih2  = (const float*)d_in[5];
    const float* Whh2  = (const float*)d_in[6];
    const float* bih2  = (const float*)d_in[7];
    const float* bhh2  = (const float*)d_in[8];
    const float* Wih3  = (const float*)d_in[9];
    const float* Whh3  = (const float*)d_in[10];
    const float* bih3  = (const float*)d_in[11];
    const float* bhh3  = (const float*)d_in[12];
    const float* mask1 = (const float*)d_in[13];
    const float* mask2 = (const float*)d_in[14];
    const float* mask3 = (const float*)d_in[15];
    float* out = (float*)d_out;

    lstm3_fused_kernel<<<dim3(B), dim3(192), 0, stream>>>(
        x, Wih1, Whh1, bih1, bhh1,
        Wih2, Whh2, bih2, bhh2,
        Wih3, Whh3, bih3, bhh3,
        mask1, mask2, mask3, out);
}